// Round 1
// baseline (975.894 us; speedup 1.0000x reference)
//
#include <hip/hip_runtime.h>
#include <hip/hip_bf16.h>
#include <stdint.h>

// ---------------- problem constants ----------------
#define IN_F   512
#define OUT_F  100000
#define NROWS  1024
#define KEXP   1536          // K expanded 3x: A' = [hi|hi|lo], B' = [hi|lo|hi]
#define NPAD   100096        // 782 * 128 (pad B rows so GEMM staging stays in-bounds)

#define COS_M  0.8775825618903728f
#define SIN_M  0.479425538604203f
#define TH_C   (-0.8775825618903728f)
#define MM_C   0.2397127693021015f
#define SCALE_C 30.0f

typedef __bf16 bf16x8 __attribute__((ext_vector_type(8)));
typedef float  f32x4  __attribute__((ext_vector_type(4)));

// ---------------- helpers ----------------
__device__ __forceinline__ ushort f2bf_rne(float f) {
  uint u = __float_as_uint(f);
  uint r = (u + 0x7fffu + ((u >> 16) & 1u)) >> 16;
  return (ushort)r;
}
__device__ __forceinline__ float bf2f(ushort b) {
  return __uint_as_float(((uint)b) << 16);
}

typedef __attribute__((address_space(1))) void gvoid_t;
typedef __attribute__((address_space(3))) void svoid_t;

__device__ __forceinline__ void gload_lds16(const void* g, void* l) {
#if defined(__has_builtin) && __has_builtin(__builtin_amdgcn_global_load_lds)
  __builtin_amdgcn_global_load_lds((const gvoid_t*)g, (svoid_t*)l, 16, 0, 0);
#else
  *(uint4*)l = *(const uint4*)g;   // synchronous fallback; barriers still make it correct
#endif
}

// ---------------- kernel 1/2: L2-normalize rows, split fp32 -> bf16 hi+lo, expand along K
// dst row layout (KEXP=1536): [0,512) = hi ; [hi2_off, +512) = hi ; [lo_off, +512) = lo
// rows >= nvalid are zero-filled (padding rows for the GEMM).
__global__ void norm_expand(const float* __restrict__ src, ushort* __restrict__ dst,
                            int nvalid, int lo_off, int hi2_off) {
  int row  = blockIdx.x * 4 + (threadIdx.x >> 6);   // one wave per row
  int lane = threadIdx.x & 63;
  ushort* orow = dst + (size_t)row * KEXP;

  if (row >= nvalid) {                // zero padding rows (ws is poisoned 0xAA)
    uint* o32 = (uint*)orow;          // 1536*2B = 768 uints
#pragma unroll
    for (int i = 0; i < 12; ++i) o32[i * 64 + lane] = 0u;
    return;
  }

  const float4* srow = (const float4*)(src + (size_t)row * IN_F);
  float4 v0 = srow[lane];
  float4 v1 = srow[lane + 64];
  float ss = v0.x*v0.x + v0.y*v0.y + v0.z*v0.z + v0.w*v0.w
           + v1.x*v1.x + v1.y*v1.y + v1.z*v1.z + v1.w*v1.w;
#pragma unroll
  for (int off = 32; off > 0; off >>= 1) ss += __shfl_xor(ss, off);
  float inv = 1.0f / fmaxf(sqrtf(ss), 1e-12f);   // matches F.normalize eps semantics

  float e[8] = {v0.x, v0.y, v0.z, v0.w, v1.x, v1.y, v1.z, v1.w};
  ushort h[8], l[8];
#pragma unroll
  for (int j = 0; j < 8; ++j) {
    float xn = e[j] * inv;
    h[j] = f2bf_rne(xn);
    l[j] = f2bf_rne(xn - bf2f(h[j]));
  }
  // two 4-element groups: cols lane*4 and 256+lane*4
#pragma unroll
  for (int g = 0; g < 2; ++g) {
    int c = g * 256 + lane * 4;
    ushort4 hv = make_ushort4(h[g*4+0], h[g*4+1], h[g*4+2], h[g*4+3]);
    ushort4 lv = make_ushort4(l[g*4+0], l[g*4+1], l[g*4+2], l[g*4+3]);
    *(ushort4*)(orow + c)            = hv;   // hi block
    *(ushort4*)(orow + hi2_off + c)  = hv;   // second hi block
    *(ushort4*)(orow + lo_off + c)   = lv;   // lo block
  }
}

// ---------------- kernel 3: bf16 TN GEMM, C[1024][100000] = A'[1024][1536] * B'[100096][1536]^T
// m97-style 128x128 tile, BK=64, 4 waves (2x2), 16x16x32 MFMA, global_load_lds width-16.
#define BM 128
#define BN 128
#define BK 64
#define NKT (KEXP / BK)   // 24

__global__ __launch_bounds__(256)
void gemm_kernel(const ushort* __restrict__ Aexp, const ushort* __restrict__ Bexp,
                 float* __restrict__ C) {
  __shared__ ushort As[BM][BK];   // 16 KB
  __shared__ ushort Bs[BN][BK];   // 16 KB

  const int tid  = threadIdx.x;
  const int bid  = blockIdx.x;
  const int mb   = bid & 7;        // m fast: 8 consecutive blocks share one B tile (L2/LLC reuse)
  const int nb   = bid >> 3;
  const int m0   = mb * BM;
  const int n0   = nb * BN;
  const int wid  = tid >> 6;
  const int lane = tid & 63;
  const int wr   = wid >> 1;       // wave row (2x2 wave grid, 64x64 out per wave)
  const int wc   = wid & 1;
  const int fr   = lane & 15;      // fragment row/col within 16
  const int fq   = lane >> 4;      // k-granule 0..3

  f32x4 acc[4][4] = {};

  // staging source pointers: thread t covers tile element offset t*8 (+pass*2048)
  const ushort* ga = Aexp + (size_t)(m0 + tid / 8) * KEXP + (tid % 8) * 8;
  const ushort* gb = Bexp + (size_t)(n0 + tid / 8) * KEXP + (tid % 8) * 8;
  ushort* la = &As[0][0] + tid * 8;
  ushort* lb = &Bs[0][0] + tid * 8;

  for (int kt = 0; kt < NKT; ++kt) {
    const int k0 = kt * BK;
    __syncthreads();               // previous tile fully consumed before overwrite
#pragma unroll
    for (int p = 0; p < 4; ++p) {  // 4 passes x 256 thr x 16B = 16 KB per tile
      gload_lds16(ga + k0 + (size_t)p * 32 * KEXP, la + p * 2048);
      gload_lds16(gb + k0 + (size_t)p * 32 * KEXP, lb + p * 2048);
    }
    __syncthreads();               // staging complete (compiler drains vmcnt before barrier)

#pragma unroll
    for (int kk = 0; kk < 2; ++kk) {
      bf16x8 af[4], bfr[4];
#pragma unroll
      for (int i = 0; i < 4; ++i) {
        af[i]  = *(const bf16x8*)&As[wr * 64 + i * 16 + fr][kk * 32 + fq * 8];
        bfr[i] = *(const bf16x8*)&Bs[wc * 64 + i * 16 + fr][kk * 32 + fq * 8];
      }
#pragma unroll
      for (int i = 0; i < 4; ++i)
#pragma unroll
        for (int j = 0; j < 4; ++j)
          acc[i][j] = __builtin_amdgcn_mfma_f32_16x16x32_bf16(af[i], bfr[j], acc[i][j], 0, 0, 0);
    }
  }

  // epilogue: C/D layout (16x16x32): col = lane&15, row = (lane>>4)*4 + reg
  const int orow0 = m0 + wr * 64 + fq * 4;
  const int ocol0 = n0 + wc * 64 + fr;
#pragma unroll
  for (int i = 0; i < 4; ++i) {
#pragma unroll
    for (int j = 0; j < 4; ++j) {
      int col = ocol0 + j * 16;
      if (col < OUT_F) {
        size_t base = (size_t)(orow0 + i * 16) * OUT_F + col;
#pragma unroll
        for (int r = 0; r < 4; ++r)
          C[base + (size_t)r * OUT_F] = acc[i][j][r] * SCALE_C;
      }
    }
  }
}

// ---------------- kernel 4: ArcFace margin fixup at the label column ----------------
__global__ void fixup_kernel(float* __restrict__ C, const int* __restrict__ label) {
  int row = blockIdx.x * blockDim.x + threadIdx.x;
  if (row >= NROWS) return;
  int lbl = label[row];
  size_t idx = (size_t)row * OUT_F + lbl;
  float cost = C[idx] * (1.0f / SCALE_C);
  float sint = sqrtf(fmaxf(1.0f - cost * cost, 0.0f));
  float phi  = cost * COS_M - sint * SIN_M;
  phi = (cost > TH_C) ? phi : (cost - MM_C);
  C[idx] = phi * SCALE_C;
}

// ---------------- launch ----------------
extern "C" void kernel_launch(void* const* d_in, const int* in_sizes, int n_in,
                              void* d_out, int out_size, void* d_ws, size_t ws_size,
                              hipStream_t stream) {
  const float* x     = (const float*)d_in[0];
  const float* w     = (const float*)d_in[1];
  const int*   label = (const int*)d_in[2];
  float* out = (float*)d_out;

  ushort* Aexp = (ushort*)d_ws;                               // 1024*1536*2   = 3 MB
  ushort* Bexp = Aexp + (size_t)NROWS * KEXP;                 // 100096*1536*2 = 307.5 MB

  // A' = [hi|hi|lo]  -> hi2_off=512, lo_off=1024
  norm_expand<<<NROWS / 4, 256, 0, stream>>>(x, Aexp, NROWS, /*lo_off=*/1024, /*hi2_off=*/512);
  // B' = [hi|lo|hi]  -> lo_off=512, hi2_off=1024 ; rows [100000,100096) zeroed
  norm_expand<<<NPAD / 4, 256, 0, stream>>>(w, Bexp, OUT_F, /*lo_off=*/512, /*hi2_off=*/1024);

  gemm_kernel<<<8 * (NPAD / BN), 256, 0, stream>>>(Aexp, Bexp, out);

  fixup_kernel<<<4, 256, 0, stream>>>(out, label);
}

// Round 2
// 689.446 us; speedup vs baseline: 1.4155x; 1.4155x over previous
//
#include <hip/hip_runtime.h>
#include <hip/hip_bf16.h>
#include <stdint.h>

// ---------------- problem constants ----------------
#define IN_F   512
#define OUT_F  100000
#define NROWS  1024
#define NPAD   100096        // 782 * 128 (pad B rows so GEMM staging stays in-bounds)

#define COS_M  0.8775825618903728f
#define SIN_M  0.479425538604203f
#define TH_C   (-0.8775825618903728f)
#define MM_C   0.2397127693021015f
#define SCALE_C 30.0f

typedef _Float16 f16;
typedef _Float16 f16x8 __attribute__((ext_vector_type(8)));
typedef float    f32x4 __attribute__((ext_vector_type(4)));

typedef __attribute__((address_space(1))) void gvoid_t;
typedef __attribute__((address_space(3))) void svoid_t;

__device__ __forceinline__ void gload_lds16(const void* g, void* l) {
#if defined(__has_builtin) && __has_builtin(__builtin_amdgcn_global_load_lds)
  __builtin_amdgcn_global_load_lds((const gvoid_t*)g, (svoid_t*)l, 16, 0, 0);
#else
  *(uint4*)l = *(const uint4*)g;   // synchronous fallback; barriers still make it correct
#endif
}

// ---------------- kernels 1/2: L2-normalize rows, emit fp16 ----------------
// One wave per row. Each lane owns 8 consecutive elements -> one 16B store.
// Rows >= nvalid are zero-filled (GEMM padding rows; ws is poisoned 0xAA).
__global__ void norm_f16(const float* __restrict__ src, f16* __restrict__ dst,
                         int nvalid) {
  const int row  = blockIdx.x * 4 + (threadIdx.x >> 6);
  const int lane = threadIdx.x & 63;
  f16* orow = dst + (size_t)row * IN_F;

  if (row >= nvalid) {                 // zero pad rows: 512 f16 = 1024 B = 256 uints
    uint* o32 = (uint*)orow;
#pragma unroll
    for (int i = 0; i < 4; ++i) o32[i * 64 + lane] = 0u;
    return;
  }

  const float4* srow = (const float4*)(src + (size_t)row * IN_F);
  float4 v0 = srow[lane * 2];          // elems lane*8 .. +3
  float4 v1 = srow[lane * 2 + 1];      // elems lane*8+4 .. +7
  float ss = v0.x*v0.x + v0.y*v0.y + v0.z*v0.z + v0.w*v0.w
           + v1.x*v1.x + v1.y*v1.y + v1.z*v1.z + v1.w*v1.w;
#pragma unroll
  for (int off = 32; off > 0; off >>= 1) ss += __shfl_xor(ss, off);
  float inv = 1.0f / fmaxf(sqrtf(ss), 1e-12f);   // matches F.normalize eps semantics

  f16x8 h;
  h[0] = (f16)(v0.x * inv); h[1] = (f16)(v0.y * inv);
  h[2] = (f16)(v0.z * inv); h[3] = (f16)(v0.w * inv);
  h[4] = (f16)(v1.x * inv); h[5] = (f16)(v1.y * inv);
  h[6] = (f16)(v1.z * inv); h[7] = (f16)(v1.w * inv);
  *(f16x8*)(orow + lane * 8) = h;      // one coalesced 16B store per lane
}

// ---------------- kernel 3: fp16 TN GEMM ----------------
// C[1024][100000] = A[1024][512] * B[100096][512]^T, scaled by 30.
// 256x128 tile, BK=64, 8 waves (4x2 grid, 64x64 out each), 16x16x32_f16 MFMA,
// global_load_lds width-16, proven m97-style 2-phase loop.
#define BM 256
#define BN 128
#define BK 64
#define KDIM 512
#define NKT (KDIM / BK)   // 8
#define GRID_X (4 * (NPAD / BN))   // 3128 = 8 * 391 (exactly divisible for T1 swizzle)

__global__ __launch_bounds__(512)
void gemm_kernel(const f16* __restrict__ A, const f16* __restrict__ B,
                 float* __restrict__ C) {
  __shared__ f16 As[BM][BK];   // 32 KB
  __shared__ f16 Bs[BN][BK];   // 16 KB

  const int tid  = threadIdx.x;
  // T1 XCD-aware swizzle: 3128 % 8 == 0, cpx = 391. Blocks sharing a B panel
  // (4 consecutive after mb-fast decode) land on the same XCD -> one L2 fill/panel.
  const int bid  = (blockIdx.x & 7) * (GRID_X / 8) + (blockIdx.x >> 3);
  const int mb   = bid & 3;        // m fast: 4 consecutive blocks share one B tile
  const int nb   = bid >> 2;
  const int m0   = mb * BM;
  const int n0   = nb * BN;
  const int wid  = tid >> 6;
  const int lane = tid & 63;
  const int wr   = wid >> 1;       // 0..3: wave row (4x2 wave grid)
  const int wc   = wid & 1;        // 0..1: wave col
  const int fr   = lane & 15;
  const int fq   = lane >> 4;

  f32x4 acc[4][4] = {};

  // staging: thread t covers row t/8 (+pass*64), cols (t%8)*8 .. +7
  const f16* ga = A + (size_t)(m0 + tid / 8) * KDIM + (tid % 8) * 8;
  const f16* gb = B + (size_t)(n0 + tid / 8) * KDIM + (tid % 8) * 8;
  f16* la = &As[0][0] + tid * 8;   // 512 thr x 8 f16 = 4096 elems per pass
  f16* lb = &Bs[0][0] + tid * 8;

  for (int kt = 0; kt < NKT; ++kt) {
    const int k0 = kt * BK;
    __syncthreads();               // previous tile fully consumed before overwrite
#pragma unroll
    for (int p = 0; p < 4; ++p)    // A tile: 256x64 = 16384 elems = 4 passes
      gload_lds16(ga + k0 + (size_t)p * 64 * KDIM, la + p * 4096);
#pragma unroll
    for (int p = 0; p < 2; ++p)    // B tile: 128x64 = 8192 elems = 2 passes
      gload_lds16(gb + k0 + (size_t)p * 64 * KDIM, lb + p * 4096);
    __syncthreads();               // staging complete (compiler drains vmcnt)

#pragma unroll
    for (int kk = 0; kk < 2; ++kk) {
      f16x8 af[4], bfr[4];
#pragma unroll
      for (int i = 0; i < 4; ++i) {
        af[i]  = *(const f16x8*)&As[wr * 64 + i * 16 + fr][kk * 32 + fq * 8];
        bfr[i] = *(const f16x8*)&Bs[wc * 64 + i * 16 + fr][kk * 32 + fq * 8];
      }
#pragma unroll
      for (int i = 0; i < 4; ++i)
#pragma unroll
        for (int j = 0; j < 4; ++j)
          acc[i][j] = __builtin_amdgcn_mfma_f32_16x16x32_f16(af[i], bfr[j], acc[i][j], 0, 0, 0);
    }
  }

  // epilogue: C/D layout (16x16x32): col = lane&15, row = (lane>>4)*4 + reg
  const int orow0 = m0 + wr * 64 + fq * 4;
  const int ocol0 = n0 + wc * 64 + fr;
#pragma unroll
  for (int i = 0; i < 4; ++i) {
#pragma unroll
    for (int j = 0; j < 4; ++j) {
      int col = ocol0 + j * 16;
      if (col < OUT_F) {
        size_t base = (size_t)(orow0 + i * 16) * OUT_F + col;
#pragma unroll
        for (int r = 0; r < 4; ++r)
          C[base + (size_t)r * OUT_F] = acc[i][j][r] * SCALE_C;
      }
    }
  }
}

// ---------------- kernel 4: ArcFace margin fixup at the label column ----------------
__global__ void fixup_kernel(float* __restrict__ C, const int* __restrict__ label) {
  int row = blockIdx.x * blockDim.x + threadIdx.x;
  if (row >= NROWS) return;
  int lbl = label[row];
  size_t idx = (size_t)row * OUT_F + lbl;
  float cost = C[idx] * (1.0f / SCALE_C);
  float sint = sqrtf(fmaxf(1.0f - cost * cost, 0.0f));
  float phi  = cost * COS_M - sint * SIN_M;
  phi = (cost > TH_C) ? phi : (cost - MM_C);
  C[idx] = phi * SCALE_C;
}

// ---------------- launch ----------------
extern "C" void kernel_launch(void* const* d_in, const int* in_sizes, int n_in,
                              void* d_out, int out_size, void* d_ws, size_t ws_size,
                              hipStream_t stream) {
  const float* x     = (const float*)d_in[0];
  const float* w     = (const float*)d_in[1];
  const int*   label = (const int*)d_in[2];
  float* out = (float*)d_out;

  f16* Aexp = (f16*)d_ws;                                // 1024*512*2   = 1 MB
  f16* Bexp = Aexp + (size_t)NROWS * IN_F;               // 100096*512*2 = 102.5 MB

  norm_f16<<<NROWS / 4, 256, 0, stream>>>(x, Aexp, NROWS);
  norm_f16<<<NPAD / 4, 256, 0, stream>>>(w, Bexp, OUT_F);

  gemm_kernel<<<GRID_X, 512, 0, stream>>>(Aexp, Bexp, out);

  fixup_kernel<<<4, 256, 0, stream>>>(out, label);
}